// Round 1
// baseline (511.544 us; speedup 1.0000x reference)
//
#include <hip/hip_runtime.h>

// STDP delta_w:
//   tp[t] = clip(0.5*tp[t-1] + in[t], 0, 1)          per (b, pre)
//   po[t] = 0.5*po[t-1] + out[t]                     per (b, post)
//   dW[o,p] = sum_{t,b} out[t,b,o]*tp[t,b,p]  -  (sum_{t,b} out[t,b,o]*po[t,b,o]) * W[o,p]
//
// Term 1 is a GEMM with K = T*B = 1024 (flat [T,B,X] layout == [K,X] row-major).
// Term 2 factors (W constant) into coef[o] applied in the GEMM epilogue.
//
// Workspace layout: [0, 16MB) trace_pre fp32 [K=1024, PRE=4096]; then coef[4096] fp32.

#define T_STEPS 64
#define B_SZ    16
#define PRE     4096
#define POST    4096
#define K_TOT   (T_STEPS * B_SZ)   // 1024

// ---------------------------------------------------------------------------
// Kernel 1: trace_pre recurrence. One thread per (b,p); writes [K, PRE] fp32.
// Flat index trick: element (t, b, p) of [T,B,PRE] is at t*B*PRE + tid where
// tid = b*PRE + p, which is exactly row k = t*B+b of the [K, PRE] matrix.
__global__ void trace_pre_kernel(const float* __restrict__ in_spikes,
                                 float* __restrict__ tp_out) {
    const int tid = blockIdx.x * blockDim.x + threadIdx.x;   // [0, B*PRE)
    const int stride = B_SZ * PRE;
    float tp = 0.0f;
    #pragma unroll 4
    for (int t = 0; t < T_STEPS; ++t) {
        float x = in_spikes[(size_t)t * stride + tid];
        tp = 0.5f * tp + x;
        tp = fminf(fmaxf(tp, 0.0f), 1.0f);
        tp_out[(size_t)t * stride + tid] = tp;
    }
}

// ---------------------------------------------------------------------------
// Kernel 2: trace_post recurrence + coef[o] = sum_{t,b} out*po reduction.
// One thread per (b,o); atomicAdd partial (16-way contention per o).
__global__ void trace_post_kernel(const float* __restrict__ out_spikes,
                                  float* __restrict__ coef) {
    const int tid = blockIdx.x * blockDim.x + threadIdx.x;   // [0, B*POST)
    const int stride = B_SZ * POST;
    float po = 0.0f, c = 0.0f;
    #pragma unroll 4
    for (int t = 0; t < T_STEPS; ++t) {
        float x = out_spikes[(size_t)t * stride + tid];
        po = 0.5f * po + x;
        c += x * po;
    }
    atomicAdd(&coef[tid & (POST - 1)], c);
}

// ---------------------------------------------------------------------------
// Kernel 3: C[o,p] = sum_k O[k,o]*TP[k,p] - coef[o]*W[o,p]
// 128x128 block tile, BK=16, 256 threads, 8x8 microtile (2x2 of 4x4 strips).
#define BM 128
#define BN 128
#define BK 16

__global__ __launch_bounds__(256) void stdp_gemm_kernel(
        const float* __restrict__ O,     // [K, POST]  (= out_spikes flat)
        const float* __restrict__ TP,    // [K, PRE]
        const float* __restrict__ W,     // [POST, PRE]
        const float* __restrict__ coef,  // [POST]
        float* __restrict__ Cout) {      // [POST, PRE]
    __shared__ float As[BK][BM];   // As[k][m]
    __shared__ float Bs[BK][BN];   // Bs[k][n]

    const int tid = threadIdx.x;
    const int tx = tid & 15;       // n-group: strips at tx*4 and 64+tx*4 (2-way bank alias = free)
    const int ty = tid >> 4;       // m-group: strips at ty*4 and 64+ty*4
    const int m0 = blockIdx.y * BM;
    const int n0 = blockIdx.x * BN;

    float acc[8][8];
    #pragma unroll
    for (int i = 0; i < 8; ++i)
        #pragma unroll
        for (int j = 0; j < 8; ++j) acc[i][j] = 0.0f;

    // Staging indices: 2048 floats per tile, 256 threads * 2 x float4.
    const int e  = tid * 4;
    const int sr = e >> 7;         // row 0..7 (and +8 for second half)
    const int sc = e & 127;        // col, multiple of 4 -> 16B aligned

    for (int k0 = 0; k0 < K_TOT; k0 += BK) {
        const float4* ga0 = (const float4*)&O [(size_t)(k0 + sr    ) * POST + m0 + sc];
        const float4* ga1 = (const float4*)&O [(size_t)(k0 + sr + 8) * POST + m0 + sc];
        const float4* gb0 = (const float4*)&TP[(size_t)(k0 + sr    ) * PRE  + n0 + sc];
        const float4* gb1 = (const float4*)&TP[(size_t)(k0 + sr + 8) * PRE  + n0 + sc];
        float4 a0 = *ga0, a1 = *ga1, b0 = *gb0, b1 = *gb1;
        *(float4*)&As[sr    ][sc] = a0;
        *(float4*)&As[sr + 8][sc] = a1;
        *(float4*)&Bs[sr    ][sc] = b0;
        *(float4*)&Bs[sr + 8][sc] = b1;
        __syncthreads();

        #pragma unroll
        for (int k = 0; k < BK; ++k) {
            float4 va0 = *(const float4*)&As[k][ty * 4];
            float4 va1 = *(const float4*)&As[k][64 + ty * 4];
            float4 vb0 = *(const float4*)&Bs[k][tx * 4];
            float4 vb1 = *(const float4*)&Bs[k][64 + tx * 4];
            float a[8] = {va0.x, va0.y, va0.z, va0.w, va1.x, va1.y, va1.z, va1.w};
            float b[8] = {vb0.x, vb0.y, vb0.z, vb0.w, vb1.x, vb1.y, vb1.z, vb1.w};
            #pragma unroll
            for (int i = 0; i < 8; ++i)
                #pragma unroll
                for (int j = 0; j < 8; ++j)
                    acc[i][j] += a[i] * b[j];
        }
        __syncthreads();
    }

    // Epilogue: C = acc - coef[o] * W, float4 stores.
    #pragma unroll
    for (int i = 0; i < 8; ++i) {
        const int o = m0 + (i >> 2) * 64 + ty * 4 + (i & 3);
        const float cf = coef[o];
        #pragma unroll
        for (int jg = 0; jg < 2; ++jg) {
            const int p = n0 + jg * 64 + tx * 4;
            const size_t idx = (size_t)o * PRE + p;
            float4 w4 = *(const float4*)&W[idx];
            float4 r;
            r.x = acc[i][jg * 4 + 0] - cf * w4.x;
            r.y = acc[i][jg * 4 + 1] - cf * w4.y;
            r.z = acc[i][jg * 4 + 2] - cf * w4.z;
            r.w = acc[i][jg * 4 + 3] - cf * w4.w;
            *(float4*)&Cout[idx] = r;
        }
    }
}

// ---------------------------------------------------------------------------
extern "C" void kernel_launch(void* const* d_in, const int* in_sizes, int n_in,
                              void* d_out, int out_size, void* d_ws, size_t ws_size,
                              hipStream_t stream) {
    const float* in_spikes  = (const float*)d_in[0];   // [T, B, PRE]
    const float* out_spikes = (const float*)d_in[1];   // [T, B, POST]
    const float* weight     = (const float*)d_in[2];   // [POST, PRE]
    float* out = (float*)d_out;                        // [POST, PRE]

    float* tp_ws = (float*)d_ws;                                            // 16 MB
    float* coef  = (float*)((char*)d_ws + (size_t)K_TOT * PRE * sizeof(float));

    // ws is re-poisoned to 0xAA before every timed launch: zero coef each call.
    hipMemsetAsync(coef, 0, POST * sizeof(float), stream);

    trace_pre_kernel <<<(B_SZ * PRE ) / 256, 256, 0, stream>>>(in_spikes, tp_ws);
    trace_post_kernel<<<(B_SZ * POST) / 256, 256, 0, stream>>>(out_spikes, coef);

    dim3 grid(PRE / BN, POST / BM);
    stdp_gemm_kernel<<<grid, 256, 0, stream>>>(out_spikes, tp_ws, weight, coef, out);
}

// Round 2
// 193.357 us; speedup vs baseline: 2.6456x; 2.6456x over previous
//
#include <hip/hip_runtime.h>

// STDP delta_w on MI355X, bf16-MFMA formulation.
//   term1: dW1[o,p] = sum_k O[k,o]*TP[k,p], K = T*B = 1024  -> bf16 MFMA GEMM
//   term2: -coef[o]*W[o,p], coef[o] = sum_k O[k,o]*PO[k,o]  -> fp32 epilogue
// Converters write O^T and TP^T as bf16 [x][k] so GEMM fragments are
// k-contiguous (ds_read_b128-able) and global_load_lds staging is a straight
// contiguous copy (LDS dest = wave-uniform base + lane*16).
//
// ws: AT bf16 [4096][1024] (8MB) | BT bf16 [4096][1024] (8MB) | coef f32[4096]

#define T_STEPS 64
#define B_SZ    16
#define PRE     4096
#define POST    4096
#define K_TOT   1024

typedef __attribute__((ext_vector_type(8))) unsigned short ushort8;
typedef __attribute__((ext_vector_type(8))) __bf16 bf16x8;
typedef __attribute__((ext_vector_type(4))) float floatx4;

__device__ __forceinline__ unsigned short f2bf(float f) {
    unsigned int u = __float_as_uint(f);
    u += 0x7fff + ((u >> 16) & 1);          // round-to-nearest-even
    return (unsigned short)(u >> 16);
}

// ---------------------------------------------------------------------------
// trace_pre recurrence -> BT[p][k] bf16 (transposed write via LDS tile).
// Block: 256 thr = 16 b x 16 p; per-row chunk rotation staggers LDS banks.
__global__ __launch_bounds__(256) void trace_pre_bt(const float* __restrict__ in_spikes,
                                                    unsigned short* __restrict__ BT) {
    __shared__ unsigned short tile[16][K_TOT];   // [p_local][k] (rotated by p*8)
    const int tid = threadIdx.x;
    const int b  = tid >> 4;      // 0..15  (wave = 4 b-groups x 16 consecutive p)
    const int xl = tid & 15;      // p_local
    const int x0 = blockIdx.x * 16;
    const float* src = in_spikes + (size_t)b * PRE + (x0 + xl);
    float tp = 0.f;
    #pragma unroll 8
    for (int t = 0; t < T_STEPS; ++t) {
        float x = src[(size_t)t * (B_SZ * PRE)];
        tp = 0.5f * tp + x;
        tp = fminf(fmaxf(tp, 0.f), 1.f);
        tile[xl][(t * 16 + b + xl * 8) & (K_TOT - 1)] = f2bf(tp);
    }
    __syncthreads();
    const int row = tid >> 4;     // output p-row 0..15
    const int c0  = tid & 15;
    #pragma unroll
    for (int i = 0; i < 8; ++i) {
        int ch = c0 + i * 16;     // k-chunk 0..127
        ushort8 v = *(const ushort8*)&tile[row][((ch + row) & 127) * 8];
        *(ushort8*)&BT[(size_t)(x0 + row) * K_TOT + ch * 8] = v;
    }
}

// ---------------------------------------------------------------------------
// out_spikes cast -> AT[o][k] bf16 (transposed) + trace_post recurrence
// + coef[o] = sum_{t,b} o*po (block-local LDS reduction, no atomics).
__global__ __launch_bounds__(256) void conv_o_at(const float* __restrict__ out_spikes,
                                                 unsigned short* __restrict__ AT,
                                                 float* __restrict__ coef) {
    __shared__ unsigned short tile[16][K_TOT];
    __shared__ float cbuf[16][17];
    const int tid = threadIdx.x;
    const int b  = tid >> 4;
    const int xl = tid & 15;      // o_local
    const int x0 = blockIdx.x * 16;
    const float* src = out_spikes + (size_t)b * POST + (x0 + xl);
    float po = 0.f, c = 0.f;
    #pragma unroll 8
    for (int t = 0; t < T_STEPS; ++t) {
        float x = src[(size_t)t * (B_SZ * POST)];
        po = 0.5f * po + x;       // update first, then multiply (matches ref)
        c += x * po;
        tile[xl][(t * 16 + b + xl * 8) & (K_TOT - 1)] = f2bf(x);
    }
    cbuf[b][xl] = c;
    __syncthreads();
    if (tid < 16) {
        float s = 0.f;
        #pragma unroll
        for (int bb = 0; bb < 16; ++bb) s += cbuf[bb][tid];
        coef[x0 + tid] = s;
    }
    const int row = tid >> 4;
    const int c0  = tid & 15;
    #pragma unroll
    for (int i = 0; i < 8; ++i) {
        int ch = c0 + i * 16;
        ushort8 v = *(const ushort8*)&tile[row][((ch + row) & 127) * 8];
        *(ushort8*)&AT[(size_t)(x0 + row) * K_TOT + ch * 8] = v;
    }
}

// ---------------------------------------------------------------------------
// bf16 MFMA GEMM, m97 structure: 128x128 tile, BK=32, 4 waves, 4x4 acc tiles.
#define BM 128
#define BN 128
#define BK 32

__device__ __forceinline__ void glds16(const void* g, void* l) {
    __builtin_amdgcn_global_load_lds((const __attribute__((address_space(1))) void*)g,
                                     (__attribute__((address_space(3))) void*)l,
                                     16, 0, 0);
}

__global__ __launch_bounds__(256) void stdp_gemm_mfma(
        const unsigned short* __restrict__ AT,   // [POST][K] bf16 bits
        const unsigned short* __restrict__ BT,   // [PRE][K]  bf16 bits
        const float* __restrict__ W,             // [POST][PRE]
        const float* __restrict__ coef,          // [POST]
        float* __restrict__ Cout) {              // [POST][PRE]
    __shared__ unsigned short As[BM][BK];        // [m][k], rows = 64 B
    __shared__ unsigned short Bs[BN][BK];
    const int tid  = threadIdx.x;
    const int lane = tid & 63;
    const int wave = tid >> 6;
    const int wm = (wave >> 1) * 64;
    const int wn = (wave & 1) * 64;
    const int m0 = blockIdx.y * BM;
    const int n0 = blockIdx.x * BN;

    floatx4 acc[4][4];
    #pragma unroll
    for (int i = 0; i < 4; ++i)
        #pragma unroll
        for (int j = 0; j < 4; ++j)
            acc[i][j] = (floatx4){0.f, 0.f, 0.f, 0.f};

    // Staging: thread tid covers tile chunk tid*16B -> LDS offset lane*16 (+wave base).
    const int srow = tid >> 2;                   // 0..63
    const int sk   = (tid & 3) * 8;
    const unsigned short* ga = &AT[(size_t)(m0 + srow) * K_TOT + sk];
    const unsigned short* gb = &BT[(size_t)(n0 + srow) * K_TOT + sk];
    unsigned short* la = &As[0][0] + (tid >> 6) * 512;   // wave-uniform base
    unsigned short* lb = &Bs[0][0] + (tid >> 6) * 512;

    const int rm = lane & 15;                    // fragment row (m or n)
    const int kq = (lane >> 4) * 8;              // fragment k offset

    for (int k0 = 0; k0 < K_TOT; k0 += BK) {
        glds16(ga,              la);             // rows 0..63
        glds16(ga + 64 * K_TOT, la + 64 * BK);   // rows 64..127
        glds16(gb,              lb);
        glds16(gb + 64 * K_TOT, lb + 64 * BK);
        ga += BK; gb += BK;
        __syncthreads();                         // drains vmcnt (compiler-inserted)

        bf16x8 af[4], bv[4];
        #pragma unroll
        for (int i = 0; i < 4; ++i) {
            af[i] = *(const bf16x8*)&As[wm + i * 16 + rm][kq];
            bv[i] = *(const bf16x8*)&Bs[wn + i * 16 + rm][kq];
        }
        #pragma unroll
        for (int mi = 0; mi < 4; ++mi)
            #pragma unroll
            for (int ni = 0; ni < 4; ++ni)
                acc[mi][ni] = __builtin_amdgcn_mfma_f32_16x16x32_bf16(
                    af[mi], bv[ni], acc[mi][ni], 0, 0, 0);
        __syncthreads();
    }

    // Epilogue: C = acc - coef[o]*W. C/D layout: col=lane&15, row=quad*4+reg.
    const int colp = n0 + wn + rm;
    const int rowb = m0 + wm + (lane >> 4) * 4;
    #pragma unroll
    for (int mi = 0; mi < 4; ++mi) {
        #pragma unroll
        for (int r = 0; r < 4; ++r) {
            const int o = rowb + mi * 16 + r;
            const float cf = coef[o];
            const float* wr = &W[(size_t)o * PRE];
            float* cr = &Cout[(size_t)o * PRE];
            #pragma unroll
            for (int ni = 0; ni < 4; ++ni) {
                const int p = colp + ni * 16;
                cr[p] = acc[mi][ni][r] - cf * wr[p];
            }
        }
    }
}

// ---------------------------------------------------------------------------
extern "C" void kernel_launch(void* const* d_in, const int* in_sizes, int n_in,
                              void* d_out, int out_size, void* d_ws, size_t ws_size,
                              hipStream_t stream) {
    const float* in_spikes  = (const float*)d_in[0];
    const float* out_spikes = (const float*)d_in[1];
    const float* weight     = (const float*)d_in[2];
    float* out = (float*)d_out;

    unsigned short* AT = (unsigned short*)d_ws;                 // 8 MB
    unsigned short* BT = AT + (size_t)POST * K_TOT;             // 8 MB
    float* coef = (float*)(BT + (size_t)PRE * K_TOT);           // 16 KB

    trace_pre_bt<<<PRE  / 16, 256, 0, stream>>>(in_spikes, BT);
    conv_o_at  <<<POST / 16, 256, 0, stream>>>(out_spikes, AT, coef);

    dim3 grid(PRE / BN, POST / BM);
    stdp_gemm_mfma<<<grid, 256, 0, stream>>>(AT, BT, weight, coef, out);
}

// Round 3
// 191.295 us; speedup vs baseline: 2.6741x; 1.0108x over previous
//
#include <hip/hip_runtime.h>

// STDP delta_w on MI355X, bf16-MFMA formulation.
//   term1: dW1[o,p] = sum_k O[k,o]*TP[k,p], K = T*B = 1024  -> bf16 MFMA GEMM
//   term2: -coef[o]*W[o,p], coef[o] = sum_k O[k,o]*PO[k,o]  -> fp32 epilogue
// One merged converter kernel writes O^T and TP^T as bf16 [x][k] (k-contiguous
// fragments, glds-compatible staging) with 16-deep load batching for MLP.
// GEMM LDS uses an XOR chunk swizzle (row>>1 & 3) applied on the global side
// of global_load_lds so fragment ds_read_b128 is 2-way (free) per quarter-wave.
//
// ws: AT bf16 [4096][1024] (8MB) | BT bf16 [4096][1024] (8MB) | coef f32[4096]

#define T_STEPS 64
#define B_SZ    16
#define PRE     4096
#define POST    4096
#define K_TOT   1024

typedef __attribute__((ext_vector_type(8))) unsigned short ushort8;
typedef __attribute__((ext_vector_type(8))) __bf16 bf16x8;
typedef __attribute__((ext_vector_type(4))) float floatx4;

__device__ __forceinline__ unsigned short f2bf(float f) {
    unsigned int u = __float_as_uint(f);
    u += 0x7fff + ((u >> 16) & 1);          // round-to-nearest-even
    return (unsigned short)(u >> 16);
}

// ---------------------------------------------------------------------------
// Merged converter: blocks [0,256) do trace_pre -> BT; [256,512) do
// out_spikes cast -> AT + trace_post coef reduction. 16b x 16x threads,
// loads batched 16-deep, transposed bf16 write via rotated LDS tile.
__global__ __launch_bounds__(256) void trace_convert(
        const float* __restrict__ in_spikes,
        const float* __restrict__ out_spikes,
        unsigned short* __restrict__ AT,
        unsigned short* __restrict__ BT,
        float* __restrict__ coef) {
    __shared__ unsigned short tile[16][K_TOT];   // [x_local][k], rotated by x*8
    __shared__ float cbuf[16][17];
    const int tid = threadIdx.x;
    const int b  = tid >> 4;
    const int xl = tid & 15;
    const bool isA = blockIdx.x >= 256;
    const int x0 = (isA ? blockIdx.x - 256 : blockIdx.x) * 16;
    const float* src = (isA ? out_spikes : in_spikes) + (size_t)b * 4096 + x0 + xl;
    unsigned short* dst = isA ? AT : BT;

    float state = 0.f, c = 0.f;
    for (int tc = 0; tc < 4; ++tc) {
        float xs[16];
        #pragma unroll
        for (int j = 0; j < 16; ++j)
            xs[j] = src[(size_t)(tc * 16 + j) * (B_SZ * PRE)];
        if (isA) {
            #pragma unroll
            for (int j = 0; j < 16; ++j) {
                const int t = tc * 16 + j;
                state = 0.5f * state + xs[j];          // po update first
                c += xs[j] * state;                    // then o*po (matches ref)
                tile[xl][(t * 16 + b + xl * 8) & (K_TOT - 1)] = f2bf(xs[j]);
            }
        } else {
            #pragma unroll
            for (int j = 0; j < 16; ++j) {
                const int t = tc * 16 + j;
                state = fminf(fmaxf(0.5f * state + xs[j], 0.f), 1.f);
                tile[xl][(t * 16 + b + xl * 8) & (K_TOT - 1)] = f2bf(state);
            }
        }
    }
    if (isA) cbuf[b][xl] = c;
    __syncthreads();
    if (isA && tid < 16) {
        float s = 0.f;
        #pragma unroll
        for (int bb = 0; bb < 16; ++bb) s += cbuf[bb][tid];
        coef[x0 + tid] = s;
    }
    const int row = tid >> 4;
    const int c0  = tid & 15;
    #pragma unroll
    for (int i = 0; i < 8; ++i) {
        const int ch = c0 + i * 16;                    // k-chunk 0..127
        ushort8 v = *(const ushort8*)&tile[row][((ch + row) & 127) * 8];
        *(ushort8*)&dst[(size_t)(x0 + row) * K_TOT + ch * 8] = v;
    }
}

// ---------------------------------------------------------------------------
// bf16 MFMA GEMM: 128x128 tile, BK=32, 4 waves, 4x4 16x16x32 tiles,
// glds width-16 staging, XOR chunk swizzle for conflict-free ds_read_b128.
#define BM 128
#define BN 128
#define BK 32

__device__ __forceinline__ void glds16(const void* g, void* l) {
    __builtin_amdgcn_global_load_lds((const __attribute__((address_space(1))) void*)g,
                                     (__attribute__((address_space(3))) void*)l,
                                     16, 0, 0);
}

__global__ __launch_bounds__(256) void stdp_gemm_mfma(
        const unsigned short* __restrict__ AT,   // [POST][K] bf16 bits
        const unsigned short* __restrict__ BT,   // [PRE][K]  bf16 bits
        const float* __restrict__ W,             // [POST][PRE]
        const float* __restrict__ coef,          // [POST]
        float* __restrict__ Cout) {              // [POST][PRE]
    __shared__ unsigned short As[BM][BK];        // [m][k-chunk swizzled]
    __shared__ unsigned short Bs[BN][BK];
    const int tid  = threadIdx.x;
    const int lane = tid & 63;
    const int wave = tid >> 6;
    const int wm = (wave >> 1) * 64;
    const int wn = (wave & 1) * 64;
    const int m0 = blockIdx.y * BM;
    const int n0 = blockIdx.x * BN;

    floatx4 acc[4][4];
    #pragma unroll
    for (int i = 0; i < 4; ++i)
        #pragma unroll
        for (int j = 0; j < 4; ++j)
            acc[i][j] = (floatx4){0.f, 0.f, 0.f, 0.f};

    // Staging: LDS slot [srow][tid&3] receives global chunk (tid&3)^((srow>>1)&3).
    const int srow = tid >> 2;                   // 0..63
    const int qg   = (tid & 3) ^ ((srow >> 1) & 3);
    const unsigned short* ga = &AT[(size_t)(m0 + srow) * K_TOT + qg * 8];
    const unsigned short* gb = &BT[(size_t)(n0 + srow) * K_TOT + qg * 8];
    unsigned short* la = &As[0][0] + wave * 512;  // wave-uniform base
    unsigned short* lb = &Bs[0][0] + wave * 512;

    const int rm  = lane & 15;                   // fragment row (m or n)
    const int q   = lane >> 4;                   // global k-chunk wanted
    const int kqs = (q ^ ((rm >> 1) & 3)) * 8;   // swizzled LDS position

    for (int k0 = 0; k0 < K_TOT; k0 += BK) {
        glds16(ga,              la);             // rows 0..63
        glds16(ga + 64 * K_TOT, la + 64 * BK);   // rows 64..127
        glds16(gb,              lb);
        glds16(gb + 64 * K_TOT, lb + 64 * BK);
        ga += BK; gb += BK;
        __syncthreads();

        bf16x8 af[4], bv[4];
        #pragma unroll
        for (int i = 0; i < 4; ++i) {
            af[i] = *(const bf16x8*)&As[wm + i * 16 + rm][kqs];
            bv[i] = *(const bf16x8*)&Bs[wn + i * 16 + rm][kqs];
        }
        #pragma unroll
        for (int mi = 0; mi < 4; ++mi)
            #pragma unroll
            for (int ni = 0; ni < 4; ++ni)
                acc[mi][ni] = __builtin_amdgcn_mfma_f32_16x16x32_bf16(
                    af[mi], bv[ni], acc[mi][ni], 0, 0, 0);
        __syncthreads();
    }

    // Epilogue: C = acc - coef[o]*W. C/D layout: col=lane&15, row=quad*4+reg.
    const int colp = n0 + wn + rm;
    const int rowb = m0 + wm + (lane >> 4) * 4;
    #pragma unroll
    for (int mi = 0; mi < 4; ++mi) {
        #pragma unroll
        for (int r = 0; r < 4; ++r) {
            const int o = rowb + mi * 16 + r;
            const float cf = coef[o];
            const float* wr = &W[(size_t)o * PRE];
            float* cr = &Cout[(size_t)o * PRE];
            #pragma unroll
            for (int ni = 0; ni < 4; ++ni) {
                const int p = colp + ni * 16;
                cr[p] = acc[mi][ni][r] - cf * wr[p];
            }
        }
    }
}

// ---------------------------------------------------------------------------
extern "C" void kernel_launch(void* const* d_in, const int* in_sizes, int n_in,
                              void* d_out, int out_size, void* d_ws, size_t ws_size,
                              hipStream_t stream) {
    const float* in_spikes  = (const float*)d_in[0];
    const float* out_spikes = (const float*)d_in[1];
    const float* weight     = (const float*)d_in[2];
    float* out = (float*)d_out;

    unsigned short* AT = (unsigned short*)d_ws;                 // 8 MB
    unsigned short* BT = AT + (size_t)POST * K_TOT;             // 8 MB
    float* coef = (float*)(BT + (size_t)PRE * K_TOT);           // 16 KB

    trace_convert<<<512, 256, 0, stream>>>(in_spikes, out_spikes, AT, BT, coef);

    dim3 grid(PRE / BN, POST / BM);
    stdp_gemm_mfma<<<grid, 256, 0, stream>>>(AT, BT, weight, coef, out);
}